// Round 14
// baseline (303.423 us; speedup 1.0000x reference)
//
#include <hip/hip_runtime.h>
#include <hip/hip_bf16.h>
#include <hip/hip_cooperative_groups.h>

namespace cg = cooperative_groups;

#define KK 5
constexpr int N0 = 78400;     // B*28*28
constexpr int E0 = 627200;    // N0*8
constexpr int N1 = 19600;     // B*14*14
constexpr int E1 = 156800;    // N1*8
constexpr int C1 = 32, C2 = 64;
constexpr int BSZ = 100;
constexpr int FC1_IN = 3136, FC1_OUT = 512;
constexpr int KEXT = 832;     // 800 tap-space + 32 root channels
constexpr int ULS = 836;      // LDS int/fp32 U row stride
constexpr int UBS = 856;      // LDS bf16 U row stride (ushorts)
constexpr int KZ = 7;         // fc1 K-splits

// block-granularity buckets (no fine sort; conv blocks consume unordered)
constexpr int NB0 = 1400;     // E0: 56-node buckets
constexpr int CAP0 = 576;     // mean 448 + 6 sigma
constexpr int NB1 = 1225;     // E1: 16-node buckets
constexpr int CAP1 = 224;     // mean 128 + 8.5 sigma
constexpr int NBT = NB0 + NB1;  // 2625 counters

constexpr float SC1  = 4194304.f;  // 2^22 conv1 fixed-point scale
constexpr float ISC1 = 1.f / 4194304.f;
constexpr float SC2  = 1048576.f;  // 2^20 conv2 scale
constexpr float ISC2 = 1.f / 1048576.f;

typedef __attribute__((ext_vector_type(8))) short bf16x8;
typedef __attribute__((ext_vector_type(4))) float f32x4;

__device__ __forceinline__ unsigned short f2bf(float f) {
    union { float f; unsigned u; } v; v.f = f;
    unsigned u = v.u;
    unsigned r = (u + 0x7FFF + ((u >> 16) & 1)) >> 16;   // RNE
    return (unsigned short)r;
}
__device__ __forceinline__ float bf2f(unsigned short h) {
    return __uint_as_float(((unsigned)h) << 16);
}

// order-preserving fp32<->uint encoding for atomicMax pooling
__device__ __forceinline__ unsigned fenc(float f) {
    unsigned u = __float_as_uint(f);
    return (u & 0x80000000u) ? ~u : (u | 0x80000000u);
}
__device__ __forceinline__ unsigned short fdec_bf(unsigned e) {
    unsigned u = (e & 0x80000000u) ? (e & 0x7FFFFFFFu) : ~e;
    return f2bf(__uint_as_float(u));
}

__device__ __forceinline__ void taps4(float px, float py,
                                      int& a00, int& a01, int& a10, int& a11,
                                      float& fx, float& fy) {
    float kfx = floorf(px), kfy = floorf(py);
    fx = px - kfx; fy = py - kfy;
    int k0x = min(max((int)kfx, 0), KK - 1);
    int k0y = min(max((int)kfy, 0), KK - 1);
    int k1x = min(k0x + 1, KK - 1), k1y = min(k0y + 1, KK - 1);
    a00 = k0x * KK + k0y; a01 = k0x * KK + k1y;
    a10 = k1x * KK + k0y; a11 = k1x * KK + k1y;
}

// ---- single-pass binning + weight prep + pmax init (unchanged from r13) ----
__global__ void coarse_bin(const int* __restrict__ ei0, const int* __restrict__ ei1,
                           const float* __restrict__ ps0, const float* __restrict__ ps1,
                           int* __restrict__ gcur,
                           int2* __restrict__ pk0, int2* __restrict__ pk1,
                           const float* __restrict__ fc1w, const float* __restrict__ W2,
                           const float* __restrict__ root2,
                           unsigned short* __restrict__ wt1,
                           unsigned short* __restrict__ w2t,
                           unsigned* __restrict__ pmax) {
    __shared__ int hist[NBT];          // 10.5 KB
    __shared__ int gbase[NBT];         // 10.5 KB
    __shared__ unsigned short tile[64 * 66];
    int t = threadIdx.x;               // 512 threads
    if (blockIdx.x >= 192) {
        int pb = blockIdx.x - 192;
        if (pb >= 400) {               // ---- pmax init: 8 blocks ----
            for (int idx = (pb - 400) * 512 + t; idx < 112 * FC1_IN; idx += 8 * 512)
                pmax[idx] = (idx < 100 * FC1_IN) ? 0x007FFFFFu   // enc(-inf)
                                                 : 0x80000000u;  // enc(0.0f)
            return;
        }
        if (pb >= 392) {               // ---- w2t: 8 blocks x 6656 elems ----
            int base = (pb - 392) * 6656;
            for (int i2 = t; i2 < 6656; i2 += 512) {
                int idx = base + i2;
                int o = idx / KEXT, k = idx - o * KEXT;
                float v = (k < 800) ? W2[k * 64 + o] : root2[(k - 800) * 64 + o];
                w2t[idx] = f2bf(v);
            }
            return;
        }
        // ---- wt1 transpose: 392 blocks = 49 k-tiles x 8 j-tiles ----
        int k0 = (pb >> 3) * 64, j0 = (pb & 7) * 64;
        int jj = t & 63, ks = t >> 6;  // ks 0..7
        for (int kk = ks; kk < 64; kk += 8)
            tile[kk * 66 + jj] = f2bf(fc1w[(k0 + kk) * FC1_OUT + j0 + jj]);
        __syncthreads();
        int kk2 = t & 63, js = t >> 6;
        for (int j2 = js; j2 < 64; j2 += 8)
            wt1[(j0 + j2) * FC1_IN + k0 + kk2] = tile[kk2 * 66 + j2];
        return;
    }
    for (int i = t; i < NBT; i += 512) hist[i] = 0;
    __syncthreads();
    int e0b = blockIdx.x * 4096;
    int keys[8], rnk[8], pay0[8], pay1[8];
#pragma unroll
    for (int j = 0; j < 8; j++) {
        int e = e0b + t + j * 512;
        int k = -1, p0 = 0, p1v = 0;
        if (e < E0) {
            int dst = ei0[E0 + e];
            int b = dst / 56, low = dst - b * 56;       // low: 6 bits
            k = b;
            float px = ps0[2 * e] * 4.f, py = ps0[2 * e + 1] * 4.f;
            unsigned ux = min((unsigned)(px * 16384.f + 0.5f), 65535u);
            unsigned uy = min((unsigned)(py * 16384.f + 0.5f), 65535u);
            p0 = ei0[e] | (low << 20); p1v = (int)(ux | (uy << 16));
        } else if (e < E0 + E1) {
            int el = e - E0;
            int dst = ei1[E1 + el];
            k = NB0 + (dst >> 4);                       // 16-node bucket
            float px = ps1[2 * el] * 4.f, py = ps1[2 * el + 1] * 4.f;
            unsigned ux = min((unsigned)(px * 16384.f + 0.5f), 65535u);
            unsigned uy = min((unsigned)(py * 16384.f + 0.5f), 65535u);
            p0 = ei1[el] | ((dst & 15) << 20); p1v = (int)(ux | (uy << 16));
        }
        keys[j] = k; pay0[j] = p0; pay1[j] = p1v;
    }
#pragma unroll
    for (int j = 0; j < 8; j++)
        if (keys[j] >= 0) rnk[j] = atomicAdd(&hist[keys[j]], 1);   // native ds_add
    __syncthreads();
    for (int i = t; i < NBT; i += 512)
        gbase[i] = hist[i] ? atomicAdd(&gcur[i], hist[i]) : 0;
    __syncthreads();
#pragma unroll
    for (int j = 0; j < 8; j++) {
        if (keys[j] >= 0) {
            int k = keys[j];
            int p = gbase[k] + rnk[j];
            if (k < NB0) {
                if (p < CAP0) pk0[k * CAP0 + p] = make_int2(pay0[j], pay1[j]);
            } else {
                if (p < CAP1) pk1[(k - NB0) * CAP1 + p] = make_int2(pay0[j], pay1[j]);
            }
        }
    }
}

// ---- cooperative mega-kernel: conv1+pool1 | conv2+pool2 | fc1 | fc2+lsm.
//      grid.sync() between phases replaces 3 kernel-boundary drains.
//      All per-phase math/order identical to r13 -> bit-identical output. ----
__global__ __launch_bounds__(512)
void fused_net(const int2* __restrict__ pk0, const int2* __restrict__ pk1,
               const int* __restrict__ gcur,
               const float* __restrict__ x, const float* __restrict__ W1,
               const float* __restrict__ root1, const float* __restrict__ b1,
               const unsigned short* __restrict__ w2t, const float* __restrict__ b2,
               const unsigned short* __restrict__ wt1, const float* __restrict__ fc1b,
               const float* __restrict__ fc2w, const float* __restrict__ fc2b,
               unsigned short* __restrict__ p1b, unsigned* __restrict__ pmax,
               float* __restrict__ z1p, float* __restrict__ out) {
    cg::grid_group grid = cg::this_grid();
    __shared__ int UiS[16 * ULS];      // 53.5 KB multi-purpose region
    __shared__ int esS[CAP1];
    __shared__ int etS[CAP1];
    __shared__ float efxS[CAP1], efyS[CAP1];
    __shared__ int degc[16];
    int t = threadIdx.x;               // 512 threads
    int i = t & 31, g = t >> 5;        // ch / slot
    int wv = t >> 6, lane = t & 63, quad = lane >> 4, lrow = lane & 15;

    // ================= Phase A: conv1 + pool1 =================
    {
        int* Ui = UiS;                           // 56*26 ints
        float* h1t = (float*)(UiS + 56 * 26);    // 56*32 floats (disjoint)
        for (int bb = blockIdx.x; bb < NB0; bb += gridDim.x) {
            int n0 = bb * 56;
            for (int k = t; k < 56 * 26; k += 512) Ui[k] = 0;
            __syncthreads();
            int cnt = min(gcur[bb], CAP0);
            const int2* bkt = pk0 + bb * CAP0;
            for (int j = t; j < cnt; j += 512) {
                int2 r = bkt[j];
                int src = r.x & 0xFFFFF, low = (r.x >> 20) & 63;
                float px = (float)((unsigned)r.y & 0xFFFF) * (1.f / 16384.f);
                float py = (float)((unsigned)r.y >> 16) * (1.f / 16384.f);
                int a00, a01, a10, a11; float fx, fy;
                taps4(px, py, a00, a01, a10, a11, fx, fy);
                float xv = x[src];
                float gx = 1.f - fx, gy = 1.f - fy;
                int* row = Ui + low * 26;
                atomicAdd(row + a00, __float2int_rn(gx * gy * xv * SC1));
                atomicAdd(row + a01, __float2int_rn(gx * fy * xv * SC1));
                atomicAdd(row + a10, __float2int_rn(fx * gy * xv * SC1));
                atomicAdd(row + a11, __float2int_rn(fx * fy * xv * SC1));
                atomicAdd(row + 25, 1);
            }
            __syncthreads();
            {
                float w1c[25];
#pragma unroll
                for (int a = 0; a < 25; a++) w1c[a] = W1[a * C1 + i];
                float ro = root1[i], bo = b1[i];
#pragma unroll
                for (int j2 = 0; j2 < 4; j2++) {
                    int nl = g * 4 + j2;            // g 0..15 -> nl 0..63
                    if (nl < 56) {
                        int n = n0 + nl;
                        float acc = 0.f;
#pragma unroll
                        for (int a = 0; a < 25; a++)
                            acc += (float)Ui[nl * 26 + a] * w1c[a];
                        float invd = ISC1 / fmaxf((float)Ui[nl * 26 + 25], 1.f);
                        float v = acc * invd + x[n] * ro + bo;
                        h1t[nl * 32 + i] = v > 0.f ? v : expm1f(v);
                    }
                }
            }
            __syncthreads();
            for (int i2 = t; i2 < 448; i2 += 512) {
                int o2 = i2 & 31, pc = i2 >> 5;
                float m0 = h1t[(2 * pc) * 32 + o2],      m1 = h1t[(2 * pc + 1) * 32 + o2];
                float m2 = h1t[(28 + 2 * pc) * 32 + o2], m3 = h1t[(28 + 2 * pc + 1) * 32 + o2];
                p1b[(bb * 14 + pc) * C1 + o2] = f2bf(fmaxf(fmaxf(m0, m1), fmaxf(m2, m3)));
            }
            __syncthreads();
        }
    }
    grid.sync();
    // ================= Phase B: conv2 + pool2(atomicMax) =================
    {
        unsigned short* Ub = (unsigned short*)UiS;
        const int* cnt1 = gcur + NB0;
        for (int bx = blockIdx.x; bx < NB1; bx += gridDim.x) {
            int nb = bx * 16;
            int* up = UiS + g * ULS;
#pragma unroll
            for (int a = 0; a < 25; a++) up[a * 32 + i] = 0;
            up[800 + i] = __float2int_rn(bf2f(p1b[(nb + g) * C1 + i]) * SC2);
            if (t < 16) degc[t] = 0;
            __syncthreads();
            int cnt = min(cnt1[bx], CAP1);
            for (int j = t; j < cnt; j += 512) {
                int2 r = pk1[bx * CAP1 + j];
                esS[j] = r.x;                                  // src | node<<20
                float px = (float)((unsigned)r.y & 0xFFFF) * (1.f / 16384.f);
                float py = (float)((unsigned)r.y >> 16) * (1.f / 16384.f);
                int a00, a01, a10, a11; float fx, fy;
                taps4(px, py, a00, a01, a10, a11, fx, fy);
                etS[j] = a00 | (a01 << 5) | (a10 << 10) | (a11 << 15);
                efxS[j] = fx; efyS[j] = fy;
                atomicAdd(&degc[(r.x >> 20) & 15], 1);
            }
            __syncthreads();
            for (int j = g; j < cnt; j += 16) {
                int rx = esS[j];
                float xv = bf2f(p1b[(rx & 0xFFFFF) * C1 + i]);
                int* row = UiS + ((rx >> 20) & 15) * ULS;
                int m = etS[j];
                float fx = efxS[j], fy = efyS[j];
                float gx = 1.f - fx, gy = 1.f - fy;
                atomicAdd(row + (m & 31) * 32 + i,         __float2int_rn(gx * gy * xv * SC2));
                atomicAdd(row + ((m >> 5) & 31) * 32 + i,  __float2int_rn(gx * fy * xv * SC2));
                atomicAdd(row + ((m >> 10) & 31) * 32 + i, __float2int_rn(fx * gy * xv * SC2));
                atomicAdd(row + ((m >> 15) & 31) * 32 + i, __float2int_rn(fx * fy * xv * SC2));
            }
            __syncthreads();
            {   // int fixed-point -> bf16 (invd folded into tap part)
                float invd = 1.f / fmaxf((float)degc[g], 1.f);
                float stap = ISC2 * invd;
                const int* srcp = UiS + g * ULS + i * 26;
                float rv[26];
#pragma unroll
                for (int j = 0; j < 26; j++) {
                    float v = (float)srcp[j];
                    rv[j] = (i * 26 + j < 800) ? v * stap : v * ISC2;
                }
                __syncthreads();
                unsigned* dstp = (unsigned*)(Ub + g * UBS + i * 26);
#pragma unroll
                for (int j = 0; j < 13; j++) {
                    unsigned lo = f2bf(rv[2 * j]), hi = f2bf(rv[2 * j + 1]);
                    dstp[j] = lo | (hi << 16);
                }
            }
            __syncthreads();
            if (wv < 4) {
                f32x4 acc = {0.f, 0.f, 0.f, 0.f};
                const unsigned short* bbase = w2t + (wv * 16 + lrow) * KEXT;
                const unsigned short* abase = Ub + lrow * UBS;
#pragma unroll
                for (int kc = 0; kc < 26; kc++) {
                    bf16x8 a = *(const bf16x8*)(abase + kc * 32 + quad * 8);
                    bf16x8 b = *(const bf16x8*)(bbase + kc * 32 + quad * 8);
                    acc = __builtin_amdgcn_mfma_f32_16x16x32_bf16(a, b, acc, 0, 0, 0);
                }
                int o = wv * 16 + lrow;
                float bo = b2[o];
#pragma unroll
                for (int r = 0; r < 4; r++) {
                    int node = quad * 4 + r;
                    float v = acc[r] + bo;
                    v = v > 0.f ? v : expm1f(v);
                    int n1 = nb + node;
                    int b28 = n1 / 784;
                    int rem = n1 - b28 * 784;
                    int rr = rem / 28, cc = rem - rr * 28;
                    int flat = ((b28 * 14 + (rr >> 1)) * 14 + (cc >> 1)) * 64 + o;
                    atomicMax(&pmax[flat], fenc(v));
                }
            }
            __syncthreads();
        }
    }
    grid.sync();
    // ================= Phase C: fc1 MFMA (decode pmax in staging) =================
    {
        constexpr int AS = 232;
        unsigned short* as_ = (unsigned short*)UiS;   // 16*232 ushorts
        for (int tau = blockIdx.x; tau < 8 * 7 * KZ; tau += gridDim.x) {
            int jt = tau & 7, r2 = tau >> 3;
            int mt = r2 % 7, kz = r2 / 7;
            int m0 = mt * 16;
            int kbase = kz * 448;
            const unsigned short* bbase = wt1 + (jt * 64 + (wv & 3) * 16 + lrow) * FC1_IN + kbase;
            f32x4 acc = {0.f, 0.f, 0.f, 0.f};
            for (int ch = 0; ch < 2; ch++) {
                __syncthreads();
                for (int slot = t; slot < 448; slot += 512) {
                    int r = slot / 28, c = slot - (slot / 28) * 28;
                    const unsigned* gp = pmax + (m0 + r) * FC1_IN + kbase + ch * 224 + c * 8;
                    uint4 e0 = *(const uint4*)gp;
                    uint4 e1 = *(const uint4*)(gp + 4);
                    unsigned w0 = (unsigned)fdec_bf(e0.x) | ((unsigned)fdec_bf(e0.y) << 16);
                    unsigned w1 = (unsigned)fdec_bf(e0.z) | ((unsigned)fdec_bf(e0.w) << 16);
                    unsigned w2 = (unsigned)fdec_bf(e1.x) | ((unsigned)fdec_bf(e1.y) << 16);
                    unsigned w3 = (unsigned)fdec_bf(e1.z) | ((unsigned)fdec_bf(e1.w) << 16);
                    *(uint4*)(as_ + r * AS + c * 8) = make_uint4(w0, w1, w2, w3);
                }
                __syncthreads();
                if (wv < 4) {
                    const unsigned short* ab = as_ + lrow * AS;
                    const unsigned short* bb = bbase + ch * 224;
#pragma unroll
                    for (int kk = 0; kk < 7; kk++) {
                        bf16x8 a = *(const bf16x8*)(ab + kk * 32 + quad * 8);
                        bf16x8 b = *(const bf16x8*)(bb + kk * 32 + quad * 8);
                        acc = __builtin_amdgcn_mfma_f32_16x16x32_bf16(a, b, acc, 0, 0, 0);
                    }
                }
            }
            if (wv < 4) {
                int n = jt * 64 + wv * 16 + lrow;
#pragma unroll
                for (int r = 0; r < 4; r++) {
                    int m = m0 + quad * 4 + r;
                    z1p[kz * (112 * FC1_OUT) + m * FC1_OUT + n] = acc[r];
                }
            }
            __syncthreads();
        }
    }
    grid.sync();
    // ================= Phase D: fc2 + log_softmax =================
    if (blockIdx.x < BSZ) {
        int b = blockIdx.x;
        float* zs = (float*)UiS;
#pragma unroll
        for (int rep = 0; rep < 2; rep++) {
            int cls = wv + rep * 8;
            if (cls < 10) {
                float acc = 0.f;
#pragma unroll
                for (int m = 0; m < 8; m++) {
                    int k = lane * 8 + m;
                    float xv = fc1b[k];
#pragma unroll
                    for (int p = 0; p < KZ; p++)
                        xv += z1p[p * (112 * FC1_OUT) + b * FC1_OUT + k];
                    xv = xv > 0.f ? xv : expm1f(xv);
                    acc += xv * fc2w[k * 10 + cls];
                }
#pragma unroll
                for (int off = 32; off > 0; off >>= 1) acc += __shfl_down(acc, off);
                if (lane == 0) {
                    float z = acc + fc2b[cls];
                    zs[cls] = z > 0.f ? z : expm1f(z);
                }
            }
        }
        __syncthreads();
        if (t < 10) {
            float m = -1e30f;
            for (int jj = 0; jj < 10; jj++) m = fmaxf(m, zs[jj]);
            float s = 0.f;
            for (int jj = 0; jj < 10; jj++) s += expf(zs[jj] - m);
            out[b * 10 + t] = zs[t] - m - logf(s);
        }
    }
}

extern "C" void kernel_launch(void* const* d_in, const int* in_sizes, int n_in,
                              void* d_out, int out_size, void* d_ws, size_t ws_size,
                              hipStream_t stream) {
    const float* x     = (const float*)d_in[0];
    const float* ps0   = (const float*)d_in[1];
    const float* ps1   = (const float*)d_in[2];
    const float* W1    = (const float*)d_in[3];
    const float* root1 = (const float*)d_in[4];
    const float* b1    = (const float*)d_in[5];
    const float* W2    = (const float*)d_in[6];
    const float* root2 = (const float*)d_in[7];
    const float* b2v   = (const float*)d_in[8];
    const float* fc1w  = (const float*)d_in[9];
    const float* fc1b  = (const float*)d_in[10];
    const float* fc2w  = (const float*)d_in[11];
    const float* fc2b  = (const float*)d_in[12];
    const int*   ei0   = (const int*)d_in[13];
    const int*   ei1   = (const int*)d_in[14];

    // Workspace layout — ALL extents in 4-byte WORDS (ushort arrays: count/2).
    float* ws = (float*)d_ws;
    int*  gcur = (int*)ws;                          //      2,625 (pad -> 2,688; memset)
    int2* pk0  = (int2*)(ws + 2688);                //  1,612,800 w
    int2* pk1  = (int2*)(ws + 1615488);             //    548,800 w
    unsigned short* p1b = (unsigned short*)(ws + 2164288);  // 313,600 w
    unsigned* pmax = (unsigned*)(ws + 2477888);     //    351,232 w
    float* z1p = ws + 2829120;                      //    401,408 (7 partials)
    unsigned short* w2t = (unsigned short*)(ws + 3230528);  //  26,624 w
    unsigned short* wt1 = (unsigned short*)(ws + 3257152);  // 802,816 w
    // high water: 4,059,968 words = 16.2 MB
    float* outp = (float*)d_out;

    hipMemsetAsync(gcur, 0, (size_t)NBT * sizeof(int), stream);

    coarse_bin<<<600, 512, 0, stream>>>(ei0, ei1, ps0, ps1, gcur, pk0, pk1,
                                        fc1w, W2, root2, wt1, w2t, pmax);

    static int coopBlocks = 0;           // computed once; identical every call
    if (coopBlocks == 0) {
        int bpc = 0;
        hipOccupancyMaxActiveBlocksPerMultiprocessor(&bpc, (const void*)fused_net, 512, 0);
        if (bpc < 1) bpc = 1;
        coopBlocks = bpc * 256;
        if (coopBlocks > 1024) coopBlocks = 1024;
    }
    void* args[] = {
        (void*)&pk0, (void*)&pk1, (void*)&gcur, (void*)&x, (void*)&W1,
        (void*)&root1, (void*)&b1, (void*)&w2t, (void*)&b2v, (void*)&wt1,
        (void*)&fc1b, (void*)&fc2w, (void*)&fc2b, (void*)&p1b, (void*)&pmax,
        (void*)&z1p, (void*)&outp
    };
    hipLaunchCooperativeKernel((const void*)fused_net, dim3(coopBlocks), dim3(512),
                               args, 0, stream);
}

// Round 15
// 200.747 us; speedup vs baseline: 1.5115x; 1.5115x over previous
//
#include <hip/hip_runtime.h>
#include <hip/hip_bf16.h>

#define KK 5
constexpr int N0 = 78400;     // B*28*28
constexpr int E0 = 627200;    // N0*8
constexpr int N1 = 19600;     // B*14*14
constexpr int E1 = 156800;    // N1*8
constexpr int C1 = 32, C2 = 64;
constexpr int BSZ = 100;
constexpr int FC1_IN = 3136, FC1_OUT = 512;
constexpr int KEXT = 832;     // 800 tap-space + 32 root channels
constexpr int ULS = 836;      // LDS int/fp32 U row stride
constexpr int UBS = 856;      // LDS bf16 U row stride (ushorts)
constexpr int KZ = 7;         // fc1 K-splits

// block-granularity buckets (no fine sort; conv blocks consume unordered)
constexpr int NB0 = 1400;     // E0: 56-node buckets
constexpr int CAP0 = 576;     // mean 448 + 6 sigma
constexpr int NB1 = 1225;     // E1: 16-node buckets
constexpr int CAP1 = 224;     // mean 128 + 8.5 sigma
constexpr int NBT = NB0 + NB1;  // 2625 counters

// binning geometry: FEW blocks + two-pass so each (block,bucket) run is
// ~7-14 contiguous slots (56-112B) -> kills cross-XCD partial-line
// write amplification (~8x with 192 blocks; r8 measured 107MB WRITE).
constexpr int BIN_BLKS = 64;
constexpr int EPB = 12250;    // 64*12250 = 784,000 = E0+E1 exactly
constexpr int EITER = 24;     // ceil(12250/512)

constexpr float SC1  = 4194304.f;  // 2^22 conv1 fixed-point scale
constexpr float ISC1 = 1.f / 4194304.f;
constexpr float SC2  = 1048576.f;  // 2^20 conv2 scale
constexpr float ISC2 = 1.f / 1048576.f;

typedef __attribute__((ext_vector_type(8))) short bf16x8;
typedef __attribute__((ext_vector_type(4))) float f32x4;

__device__ __forceinline__ unsigned short f2bf(float f) {
    union { float f; unsigned u; } v; v.f = f;
    unsigned u = v.u;
    unsigned r = (u + 0x7FFF + ((u >> 16) & 1)) >> 16;   // RNE
    return (unsigned short)r;
}
__device__ __forceinline__ float bf2f(unsigned short h) {
    return __uint_as_float(((unsigned)h) << 16);
}

// order-preserving fp32<->uint encoding for atomicMax pooling
__device__ __forceinline__ unsigned fenc(float f) {
    unsigned u = __float_as_uint(f);
    return (u & 0x80000000u) ? ~u : (u | 0x80000000u);
}
__device__ __forceinline__ unsigned short fdec_bf(unsigned e) {
    unsigned u = (e & 0x80000000u) ? (e & 0x7FFFFFFFu) : ~e;
    return f2bf(__uint_as_float(u));
}

__device__ __forceinline__ void taps4(float px, float py,
                                      int& a00, int& a01, int& a10, int& a11,
                                      float& fx, float& fy) {
    float kfx = floorf(px), kfy = floorf(py);
    fx = px - kfx; fy = py - kfy;
    int k0x = min(max((int)kfx, 0), KK - 1);
    int k0y = min(max((int)kfy, 0), KK - 1);
    int k1x = min(k0x + 1, KK - 1), k1y = min(k0y + 1, KK - 1);
    a00 = k0x * KK + k0y; a01 = k0x * KK + k1y;
    a10 = k1x * KK + k0y; a11 = k1x * KK + k1y;
}

// ---- binning (two-pass, 64 blocks) + weight prep + pmax init, one launch:
//  [0,64):    edge binning into per-conv-block buckets (contiguous runs)
//  [64,456):  wt1 transpose (392)
//  [456,464): w2t build
//  [464,472): pmax init (encoded -inf; pad rows 100-111 = encoded 0)
__global__ void coarse_bin(const int* __restrict__ ei0, const int* __restrict__ ei1,
                           const float* __restrict__ ps0, const float* __restrict__ ps1,
                           int* __restrict__ gcur,
                           int2* __restrict__ pk0, int2* __restrict__ pk1,
                           const float* __restrict__ fc1w, const float* __restrict__ W2,
                           const float* __restrict__ root2,
                           unsigned short* __restrict__ wt1,
                           unsigned short* __restrict__ w2t,
                           unsigned* __restrict__ pmax) {
    __shared__ int hist[NBT];          // 10.5 KB
    __shared__ int cur[NBT];           // 10.5 KB
    __shared__ unsigned short tile[64 * 66];
    int t = threadIdx.x;               // 512 threads
    if (blockIdx.x >= BIN_BLKS) {
        int pb = blockIdx.x - BIN_BLKS;
        if (pb >= 400) {               // ---- pmax init: 8 blocks ----
            for (int idx = (pb - 400) * 512 + t; idx < 112 * FC1_IN; idx += 8 * 512)
                pmax[idx] = (idx < 100 * FC1_IN) ? 0x007FFFFFu   // enc(-inf)
                                                 : 0x80000000u;  // enc(0.0f)
            return;
        }
        if (pb >= 392) {               // ---- w2t: 8 blocks x 6656 elems ----
            int base = (pb - 392) * 6656;
            for (int i2 = t; i2 < 6656; i2 += 512) {
                int idx = base + i2;
                int o = idx / KEXT, k = idx - o * KEXT;
                float v = (k < 800) ? W2[k * 64 + o] : root2[(k - 800) * 64 + o];
                w2t[idx] = f2bf(v);
            }
            return;
        }
        // ---- wt1 transpose: 392 blocks = 49 k-tiles x 8 j-tiles ----
        int k0 = (pb >> 3) * 64, j0 = (pb & 7) * 64;
        int jj = t & 63, ks = t >> 6;  // ks 0..7
        for (int kk = ks; kk < 64; kk += 8)
            tile[kk * 66 + jj] = f2bf(fc1w[(k0 + kk) * FC1_OUT + j0 + jj]);
        __syncthreads();
        int kk2 = t & 63, js = t >> 6;
        for (int j2 = js; j2 < 64; j2 += 8)
            wt1[(j0 + j2) * FC1_IN + k0 + kk2] = tile[kk2 * 66 + j2];
        return;
    }
    // ---- edge binning, two-pass ----
    for (int i = t; i < NBT; i += 512) hist[i] = 0;
    __syncthreads();
    int ebase = blockIdx.x * EPB;
    // pass 1: count my edges per bucket
    for (int j = 0; j < EITER; j++) {
        int le = t + j * 512;
        if (le < EPB) {
            int e = ebase + le;
            int k;
            if (e < E0) k = ei0[E0 + e] / 56;
            else        k = NB0 + (ei1[E1 + (e - E0)] >> 4);
            atomicAdd(&hist[k], 1);    // native ds_add
        }
    }
    __syncthreads();
    // reserve one contiguous run per (block,bucket)
    for (int i = t; i < NBT; i += 512)
        cur[i] = hist[i] ? atomicAdd(&gcur[i], hist[i]) : 0;
    __syncthreads();
    // pass 2: re-read, build payload, place within run (contiguous writes)
    for (int j = 0; j < EITER; j++) {
        int le = t + j * 512;
        if (le < EPB) {
            int e = ebase + le;
            if (e < E0) {
                int dst = ei0[E0 + e];
                int b = dst / 56, low = dst - b * 56;
                float px = ps0[2 * e] * 4.f, py = ps0[2 * e + 1] * 4.f;
                unsigned ux = min((unsigned)(px * 16384.f + 0.5f), 65535u);
                unsigned uy = min((unsigned)(py * 16384.f + 0.5f), 65535u);
                int p = atomicAdd(&cur[b], 1);
                if (p < CAP0)
                    pk0[b * CAP0 + p] = make_int2(ei0[e] | (low << 20),
                                                  (int)(ux | (uy << 16)));
            } else {
                int el = e - E0;
                int dst = ei1[E1 + el];
                int b = dst >> 4;
                float px = ps1[2 * el] * 4.f, py = ps1[2 * el + 1] * 4.f;
                unsigned ux = min((unsigned)(px * 16384.f + 0.5f), 65535u);
                unsigned uy = min((unsigned)(py * 16384.f + 0.5f), 65535u);
                int p = atomicAdd(&cur[NB0 + b], 1);
                if (p < CAP1)
                    pk1[b * CAP1 + p] = make_int2(ei1[el] | ((dst & 15) << 20),
                                                  (int)(ux | (uy << 16)));
            }
        }
    }
}

// ---- conv1 + pool1: block = bucket = 56 nodes. Unordered edge consumption
//      via LDS int32 fixed-point atomics (associative -> deterministic).
//      p1 stored BF16 (64B rows). ----
__global__ __launch_bounds__(256, 6)
void conv1_pool(const int2* __restrict__ pk0, const int* __restrict__ cnt0,
                const float* __restrict__ x,
                const float* __restrict__ W1,
                const float* __restrict__ root, const float* __restrict__ bias,
                unsigned short* __restrict__ p1b) {
    __shared__ int   Ui[56 * 26];     // 5.8 KB fixed-point taps+deg
    __shared__ float h1t[56 * 32];    // 7.2 KB
    int t = threadIdx.x;
    int bb = blockIdx.x;              // 1400 blocks; nodes bb*56 .. +55
    int n0 = bb * 56;
    for (int i = t; i < 56 * 26; i += 256) Ui[i] = 0;
    __syncthreads();
    int cnt = min(cnt0[bb], CAP0);
    const int2* bkt = pk0 + bb * CAP0;
    for (int j = t; j < cnt; j += 256) {
        int2 r = bkt[j];                              // sequential, coalesced
        int src = r.x & 0xFFFFF, low = (r.x >> 20) & 63;
        float px = (float)((unsigned)r.y & 0xFFFF) * (1.f / 16384.f);
        float py = (float)((unsigned)r.y >> 16) * (1.f / 16384.f);
        int a00, a01, a10, a11; float fx, fy;
        taps4(px, py, a00, a01, a10, a11, fx, fy);
        float xv = x[src];                            // 313KB array: L2-resident
        float gx = 1.f - fx, gy = 1.f - fy;
        int* row = Ui + low * 26;
        atomicAdd(row + a00, __float2int_rn(gx * gy * xv * SC1));
        atomicAdd(row + a01, __float2int_rn(gx * fy * xv * SC1));
        atomicAdd(row + a10, __float2int_rn(fx * gy * xv * SC1));
        atomicAdd(row + a11, __float2int_rn(fx * fy * xv * SC1));
        atomicAdd(row + 25, 1);
    }
    __syncthreads();
    {
        int o = t & 31, ng = t >> 5;
        float w1c[25];
#pragma unroll
        for (int a = 0; a < 25; a++) w1c[a] = W1[a * C1 + o];
        float ro = root[o], bo = bias[o];
        for (int j2 = 0; j2 < 7; j2++) {
            int nl = ng * 7 + j2;
            int n = n0 + nl;
            float acc = 0.f;
#pragma unroll
            for (int a = 0; a < 25; a++) acc += (float)Ui[nl * 26 + a] * w1c[a];
            float invd = ISC1 / fmaxf((float)Ui[nl * 26 + 25], 1.f);
            float v = acc * invd + x[n] * ro + bo;
            h1t[nl * 32 + o] = v > 0.f ? v : expm1f(v);
        }
    }
    __syncthreads();
    for (int i2 = t; i2 < 448; i2 += 256) {
        int o2 = i2 & 31, pc = i2 >> 5;
        float m0 = h1t[(2 * pc) * 32 + o2],      m1 = h1t[(2 * pc + 1) * 32 + o2];
        float m2 = h1t[(28 + 2 * pc) * 32 + o2], m3 = h1t[(28 + 2 * pc + 1) * 32 + o2];
        p1b[(bb * 14 + pc) * C1 + o2] = f2bf(fmaxf(fmaxf(m0, m1), fmaxf(m2, m3)));
    }
}

// ---- conv2 fused (MFMA): block = bucket = 16 nodes, 512 threads.
//      Gather reads BF16 p1 rows (64B). Epilogue pools via order-encoded
//      global atomicMax into pmax (exact max, deterministic). ----
__global__ __launch_bounds__(512, 2)
void conv2_fused(const unsigned short* __restrict__ p1b, const int2* __restrict__ pk1,
                 const int* __restrict__ cnt1,
                 const unsigned short* __restrict__ w2t,
                 const float* __restrict__ b2, unsigned* __restrict__ pmax) {
    __shared__ int   Ui[16 * ULS];          // 53.5 KB fixed-point (bf16 aliases)
    __shared__ int   es[CAP1];
    __shared__ int   et[CAP1];
    __shared__ float efx[CAP1], efy[CAP1];
    __shared__ int   degc[16];
    unsigned short* Ub = (unsigned short*)Ui;
    int t = threadIdx.x;
    int bx = blockIdx.x;                    // 1225 blocks; nodes bx*16..+15
    int nb = bx * 16;
    int i = t & 31;                         // channel
    int g = t >> 5;                         // node slot 0..15
    int* up = Ui + g * ULS;
#pragma unroll
    for (int a = 0; a < 25; a++) up[a * 32 + i] = 0;
    up[800 + i] = __float2int_rn(bf2f(p1b[(nb + g) * C1 + i]) * SC2);   // root
    if (t < 16) degc[t] = 0;
    __syncthreads();
    int cnt = min(cnt1[bx], CAP1);
    for (int j = t; j < cnt; j += 512) {
        int2 r = pk1[bx * CAP1 + j];                  // sequential, coalesced
        es[j] = r.x;                                  // src | node<<20
        float px = (float)((unsigned)r.y & 0xFFFF) * (1.f / 16384.f);
        float py = (float)((unsigned)r.y >> 16) * (1.f / 16384.f);
        int a00, a01, a10, a11; float fx, fy;
        taps4(px, py, a00, a01, a10, a11, fx, fy);
        et[j] = a00 | (a01 << 5) | (a10 << 10) | (a11 << 15);
        efx[j] = fx; efy[j] = fy;
        atomicAdd(&degc[(r.x >> 20) & 15], 1);
    }
    __syncthreads();
    // accumulate: thread (slot g, ch i) walks edges g, g+16, ...
    for (int j = g; j < cnt; j += 16) {
        int rx = es[j];
        float xv = bf2f(p1b[(rx & 0xFFFFF) * C1 + i]);
        int* row = Ui + ((rx >> 20) & 15) * ULS;
        int m = et[j];
        float fx = efx[j], fy = efy[j];
        float gx = 1.f - fx, gy = 1.f - fy;
        atomicAdd(row + (m & 31) * 32 + i,         __float2int_rn(gx * gy * xv * SC2));
        atomicAdd(row + ((m >> 5) & 31) * 32 + i,  __float2int_rn(gx * fy * xv * SC2));
        atomicAdd(row + ((m >> 10) & 31) * 32 + i, __float2int_rn(fx * gy * xv * SC2));
        atomicAdd(row + ((m >> 15) & 31) * 32 + i, __float2int_rn(fx * fy * xv * SC2));
    }
    __syncthreads();
    // phase 1.5: int fixed-point -> bf16 (invd folded into tap part)
    {
        int g2 = t >> 5, i2c = t & 31;
        float invd = 1.f / fmaxf((float)degc[g2], 1.f);
        float stap = ISC2 * invd;
        const int* srcp = Ui + g2 * ULS + i2c * 26;
        float rv[26];
#pragma unroll
        for (int j = 0; j < 26; j++) {
            float v = (float)srcp[j];
            rv[j] = (i2c * 26 + j < 800) ? v * stap : v * ISC2;
        }
        __syncthreads();
        unsigned* dstp = (unsigned*)(Ub + g2 * UBS + i2c * 26);
#pragma unroll
        for (int j = 0; j < 13; j++) {
            unsigned lo = f2bf(rv[2 * j]), hi = f2bf(rv[2 * j + 1]);
            dstp[j] = lo | (hi << 16);
        }
    }
    __syncthreads();
    // phase 2: MFMA, waves 0-3. D[node=quad*4+r][o=wv*16+(lane&15)]
    int wv = t >> 6, lane = t & 63, quad = lane >> 4, lrow = lane & 15;
    if (wv < 4) {
        f32x4 acc = {0.f, 0.f, 0.f, 0.f};
        const unsigned short* bbase = w2t + (wv * 16 + lrow) * KEXT;
        const unsigned short* abase = Ub + lrow * UBS;   // A row = node lrow
#pragma unroll
        for (int kc = 0; kc < 26; kc++) {
            bf16x8 a = *(const bf16x8*)(abase + kc * 32 + quad * 8);
            bf16x8 b = *(const bf16x8*)(bbase + kc * 32 + quad * 8);
            acc = __builtin_amdgcn_mfma_f32_16x16x32_bf16(a, b, acc, 0, 0, 0);
        }
        int o = wv * 16 + lrow;
        float bo = b2[o];
#pragma unroll
        for (int r = 0; r < 4; r++) {
            int node = quad * 4 + r;
            float v = acc[r] + bo;
            v = v > 0.f ? v : expm1f(v);
            int n1 = nb + node;
            int b28 = n1 / 784;
            int rem = n1 - b28 * 784;
            int rr = rem / 28, cc = rem - rr * 28;
            int flat = ((b28 * 14 + (rr >> 1)) * 14 + (cc >> 1)) * 64 + o;
            atomicMax(&pmax[flat], fenc(v));
        }
    }
}

// ---- fc1 MFMA: pooled A decoded from pmax during staging; 7 kz splits. ----
__global__ void gemm_fc1(const unsigned* __restrict__ pmax,
                         const unsigned short* __restrict__ wt1,
                         float* __restrict__ z1p) {
    constexpr int AS = 232;
    __shared__ unsigned short as_[16 * AS];
    int t = threadIdx.x;
    int jt = blockIdx.x, mt = blockIdx.y, kz = blockIdx.z;
    int wv = t >> 6, lane = t & 63, quad = lane >> 4, lrow = lane & 15;
    int m0 = mt * 16;
    int kbase = kz * 448;
    const unsigned short* bbase = wt1 + (jt * 64 + wv * 16 + lrow) * FC1_IN + kbase;
    f32x4 acc = {0.f, 0.f, 0.f, 0.f};
    for (int ch = 0; ch < 2; ch++) {
        __syncthreads();
        for (int slot = t; slot < 448; slot += 256) {
            int r = slot / 28, c = slot - (slot / 28) * 28;
            const unsigned* gp = pmax + (m0 + r) * FC1_IN + kbase + ch * 224 + c * 8;
            uint4 e0 = *(const uint4*)gp;
            uint4 e1 = *(const uint4*)(gp + 4);
            unsigned w0 = (unsigned)fdec_bf(e0.x) | ((unsigned)fdec_bf(e0.y) << 16);
            unsigned w1 = (unsigned)fdec_bf(e0.z) | ((unsigned)fdec_bf(e0.w) << 16);
            unsigned w2 = (unsigned)fdec_bf(e1.x) | ((unsigned)fdec_bf(e1.y) << 16);
            unsigned w3 = (unsigned)fdec_bf(e1.z) | ((unsigned)fdec_bf(e1.w) << 16);
            *(uint4*)(as_ + r * AS + c * 8) = make_uint4(w0, w1, w2, w3);
        }
        __syncthreads();
        const unsigned short* ab = as_ + lrow * AS;
        const unsigned short* bb = bbase + ch * 224;
#pragma unroll
        for (int kk = 0; kk < 7; kk++) {
            bf16x8 a = *(const bf16x8*)(ab + kk * 32 + quad * 8);
            bf16x8 b = *(const bf16x8*)(bb + kk * 32 + quad * 8);
            acc = __builtin_amdgcn_mfma_f32_16x16x32_bf16(a, b, acc, 0, 0, 0);
        }
    }
    int n = jt * 64 + wv * 16 + lrow;
#pragma unroll
    for (int r = 0; r < 4; r++) {
        int m = m0 + quad * 4 + r;
        z1p[kz * (112 * FC1_OUT) + m * FC1_OUT + n] = acc[r];
    }
}

// ---- fc2 + log_softmax fused; sums 7 fc1 partials, applies fc1 bias+ELU ----
__global__ void fc2_lsm(const float* __restrict__ z1p, const float* __restrict__ fc1b,
                        const float* __restrict__ w, const float* __restrict__ fc2b,
                        float* __restrict__ out) {
    int b = blockIdx.x;
    int t = threadIdx.x;
    int wv = t >> 6;
    int lane = t & 63;
    float acc = 0.f;
#pragma unroll
    for (int m = 0; m < 8; m++) {
        int k = lane * 8 + m;
        float xv = fc1b[k];
#pragma unroll
        for (int p = 0; p < KZ; p++)
            xv += z1p[p * (112 * FC1_OUT) + b * FC1_OUT + k];
        xv = xv > 0.f ? xv : expm1f(xv);
        acc += xv * w[k * 10 + wv];
    }
#pragma unroll
    for (int off = 32; off > 0; off >>= 1) acc += __shfl_down(acc, off);
    __shared__ float zs[10];
    if (lane == 0) {
        float z = acc + fc2b[wv];
        zs[wv] = z > 0.f ? z : expm1f(z);
    }
    __syncthreads();
    if (t < 10) {
        float m = -1e30f;
        for (int jj = 0; jj < 10; jj++) m = fmaxf(m, zs[jj]);
        float s = 0.f;
        for (int jj = 0; jj < 10; jj++) s += expf(zs[jj] - m);
        out[b * 10 + t] = zs[t] - m - logf(s);
    }
}

extern "C" void kernel_launch(void* const* d_in, const int* in_sizes, int n_in,
                              void* d_out, int out_size, void* d_ws, size_t ws_size,
                              hipStream_t stream) {
    const float* x     = (const float*)d_in[0];
    const float* ps0   = (const float*)d_in[1];
    const float* ps1   = (const float*)d_in[2];
    const float* W1    = (const float*)d_in[3];
    const float* root1 = (const float*)d_in[4];
    const float* b1    = (const float*)d_in[5];
    const float* W2    = (const float*)d_in[6];
    const float* root2 = (const float*)d_in[7];
    const float* b2v   = (const float*)d_in[8];
    const float* fc1w  = (const float*)d_in[9];
    const float* fc1b  = (const float*)d_in[10];
    const float* fc2w  = (const float*)d_in[11];
    const float* fc2b  = (const float*)d_in[12];
    const int*   ei0   = (const int*)d_in[13];
    const int*   ei1   = (const int*)d_in[14];

    // Workspace layout — ALL extents in 4-byte WORDS (ushort arrays: count/2).
    // pk0 = 1400*576 int2 = 1,612,800 w ; pk1 = 1225*224 int2 = 548,800 w
    // p1b = 19600*32 ushorts = 313,600 w
    // pmax = 112*3136 uint = 351,232 w ; w2t = 64*832 us = 26,624 w
    // wt1 = 512*3136 us = 802,816 w
    float* ws = (float*)d_ws;
    int*  gcur = (int*)ws;                          //      2,625 (pad -> 2,688; memset)
    int2* pk0  = (int2*)(ws + 2688);                //  1,612,800 w
    int2* pk1  = (int2*)(ws + 1615488);             //    548,800 w
    unsigned short* p1b = (unsigned short*)(ws + 2164288);  // 313,600 w
    unsigned* pmax = (unsigned*)(ws + 2477888);     //    351,232 w
    float* z1p = ws + 2829120;                      //    401,408 (7 partials)
    unsigned short* w2t = (unsigned short*)(ws + 3230528);  //  26,624 w
    unsigned short* wt1 = (unsigned short*)(ws + 3257152);  // 802,816 w
    // high water: 4,059,968 words = 16.2 MB

    hipMemsetAsync(gcur, 0, (size_t)NBT * sizeof(int), stream);

    coarse_bin<<<BIN_BLKS + 392 + 8 + 8, 512, 0, stream>>>(
        ei0, ei1, ps0, ps1, gcur, pk0, pk1,
        fc1w, W2, root2, wt1, w2t, pmax);
    conv1_pool<<<NB0, 256, 0, stream>>>(pk0, gcur, x, W1, root1, b1, p1b);
    conv2_fused<<<NB1, 512, 0, stream>>>(p1b, pk1, gcur + NB0, w2t, b2v, pmax);
    gemm_fc1<<<dim3(8, 7, KZ), 256, 0, stream>>>(pmax, wt1, z1p);
    fc2_lsm<<<BSZ, 640, 0, stream>>>(z1p, fc1b, fc2w, fc2b, (float*)d_out);
}

// Round 16
// 186.352 us; speedup vs baseline: 1.6282x; 1.0772x over previous
//
#include <hip/hip_runtime.h>
#include <hip/hip_bf16.h>

#define KK 5
constexpr int N0 = 78400;     // B*28*28
constexpr int E0 = 627200;    // N0*8
constexpr int N1 = 19600;     // B*14*14
constexpr int E1 = 156800;    // N1*8
constexpr int C1 = 32, C2 = 64;
constexpr int BSZ = 100;
constexpr int FC1_IN = 3136, FC1_OUT = 512;
constexpr int KEXT = 832;     // 800 tap-space + 32 root channels
constexpr int ULS = 836;      // LDS int/fp32 U row stride
constexpr int UBS = 856;      // LDS bf16 U row stride (ushorts)
constexpr int KZ = 7;         // fc1 K-splits

// block-granularity buckets (no fine sort; conv blocks consume unordered)
constexpr int NB0 = 1400;     // E0: 56-node buckets (conv1 block = bucket)
constexpr int CAP0 = 576;     // mean 448 + 6 sigma
constexpr int NB1 = 1225;     // E1: 16-node buckets (conv2 block = bucket)
constexpr int CAP1 = 224;     // mean 128 + 8.5 sigma
constexpr int NBT = NB0 + NB1;  // 2625 counters

constexpr float SC1  = 4194304.f;  // 2^22 conv1 fixed-point scale (r8-proven)
constexpr float ISC1 = 1.f / 4194304.f;
constexpr float SC2  = 1048576.f;  // 2^20 conv2 scale (range headroom)
constexpr float ISC2 = 1.f / 1048576.f;

typedef __attribute__((ext_vector_type(8))) short bf16x8;
typedef __attribute__((ext_vector_type(4))) float f32x4;

__device__ __forceinline__ unsigned short f2bf(float f) {
    union { float f; unsigned u; } v; v.f = f;
    unsigned u = v.u;
    unsigned r = (u + 0x7FFF + ((u >> 16) & 1)) >> 16;   // RNE
    return (unsigned short)r;
}
__device__ __forceinline__ float bf2f(unsigned short h) {
    return __uint_as_float(((unsigned)h) << 16);
}

// order-preserving fp32<->uint encoding for atomicMax pooling
__device__ __forceinline__ unsigned fenc(float f) {
    unsigned u = __float_as_uint(f);
    return (u & 0x80000000u) ? ~u : (u | 0x80000000u);
}
__device__ __forceinline__ unsigned short fdec_bf(unsigned e) {
    unsigned u = (e & 0x80000000u) ? (e & 0x7FFFFFFFu) : ~e;
    return f2bf(__uint_as_float(u));
}

__device__ __forceinline__ void taps4(float px, float py,
                                      int& a00, int& a01, int& a10, int& a11,
                                      float& fx, float& fy) {
    float kfx = floorf(px), kfy = floorf(py);
    fx = px - kfx; fy = py - kfy;
    int k0x = min(max((int)kfx, 0), KK - 1);
    int k0y = min(max((int)kfy, 0), KK - 1);
    int k1x = min(k0x + 1, KK - 1), k1y = min(k0y + 1, KK - 1);
    a00 = k0x * KK + k0y; a01 = k0x * KK + k1y;
    a10 = k1x * KK + k0y; a11 = k1x * KK + k1y;
}

// ---- single-pass binning + weight prep + pmax init, one launch:
//  [0,192):   edge scatter into per-conv-block buckets
//  [192,584): wt1 transpose (392)
//  [584,592): w2t build
//  [592,600): pmax init (encoded -inf; pad rows 100-111 = encoded 0)
__global__ void coarse_bin(const int* __restrict__ ei0, const int* __restrict__ ei1,
                           const float* __restrict__ ps0, const float* __restrict__ ps1,
                           int* __restrict__ gcur,
                           int2* __restrict__ pk0, int2* __restrict__ pk1,
                           const float* __restrict__ fc1w, const float* __restrict__ W2,
                           const float* __restrict__ root2,
                           unsigned short* __restrict__ wt1,
                           unsigned short* __restrict__ w2t,
                           unsigned* __restrict__ pmax) {
    __shared__ int hist[NBT];          // 10.5 KB
    __shared__ int gbase[NBT];         // 10.5 KB
    __shared__ unsigned short tile[64 * 66];
    int t = threadIdx.x;               // 512 threads
    if (blockIdx.x >= 192) {
        int pb = blockIdx.x - 192;
        if (pb >= 400) {               // ---- pmax init: 8 blocks ----
            for (int idx = (pb - 400) * 512 + t; idx < 112 * FC1_IN; idx += 8 * 512)
                pmax[idx] = (idx < 100 * FC1_IN) ? 0x007FFFFFu   // enc(-inf)
                                                 : 0x80000000u;  // enc(0.0f)
            return;
        }
        if (pb >= 392) {               // ---- w2t: 8 blocks x 6656 elems ----
            int base = (pb - 392) * 6656;
            for (int i2 = t; i2 < 6656; i2 += 512) {
                int idx = base + i2;
                int o = idx / KEXT, k = idx - o * KEXT;
                float v = (k < 800) ? W2[k * 64 + o] : root2[(k - 800) * 64 + o];
                w2t[idx] = f2bf(v);
            }
            return;
        }
        // ---- wt1 transpose: 392 blocks = 49 k-tiles x 8 j-tiles ----
        int k0 = (pb >> 3) * 64, j0 = (pb & 7) * 64;
        int jj = t & 63, ks = t >> 6;  // ks 0..7
        for (int kk = ks; kk < 64; kk += 8)
            tile[kk * 66 + jj] = f2bf(fc1w[(k0 + kk) * FC1_OUT + j0 + jj]);
        __syncthreads();
        int kk2 = t & 63, js = t >> 6;
        for (int j2 = js; j2 < 64; j2 += 8)
            wt1[(j0 + j2) * FC1_IN + k0 + kk2] = tile[kk2 * 66 + j2];
        return;
    }
    for (int i = t; i < NBT; i += 512) hist[i] = 0;
    __syncthreads();
    int e0b = blockIdx.x * 4096;
    int keys[8], rnk[8], pay0[8], pay1[8];
#pragma unroll
    for (int j = 0; j < 8; j++) {
        int e = e0b + t + j * 512;
        int k = -1, p0 = 0, p1v = 0;
        if (e < E0) {
            int dst = ei0[E0 + e];
            int b = dst / 56, low = dst - b * 56;       // low: 6 bits
            k = b;
            float px = ps0[2 * e] * 4.f, py = ps0[2 * e + 1] * 4.f;
            unsigned ux = min((unsigned)(px * 16384.f + 0.5f), 65535u);
            unsigned uy = min((unsigned)(py * 16384.f + 0.5f), 65535u);
            p0 = ei0[e] | (low << 20); p1v = (int)(ux | (uy << 16));
        } else if (e < E0 + E1) {
            int el = e - E0;
            int dst = ei1[E1 + el];
            k = NB0 + (dst >> 4);                       // 16-node bucket
            float px = ps1[2 * el] * 4.f, py = ps1[2 * el + 1] * 4.f;
            unsigned ux = min((unsigned)(px * 16384.f + 0.5f), 65535u);
            unsigned uy = min((unsigned)(py * 16384.f + 0.5f), 65535u);
            p0 = ei1[el] | ((dst & 15) << 20); p1v = (int)(ux | (uy << 16));
        }
        keys[j] = k; pay0[j] = p0; pay1[j] = p1v;
    }
#pragma unroll
    for (int j = 0; j < 8; j++)
        if (keys[j] >= 0) rnk[j] = atomicAdd(&hist[keys[j]], 1);   // native ds_add
    __syncthreads();
    for (int i = t; i < NBT; i += 512)
        gbase[i] = hist[i] ? atomicAdd(&gcur[i], hist[i]) : 0;
    __syncthreads();
#pragma unroll
    for (int j = 0; j < 8; j++) {
        if (keys[j] >= 0) {
            int k = keys[j];
            int p = gbase[k] + rnk[j];
            if (k < NB0) {
                if (p < CAP0) pk0[k * CAP0 + p] = make_int2(pay0[j], pay1[j]);
            } else {
                if (p < CAP1) pk1[(k - NB0) * CAP1 + p] = make_int2(pay0[j], pay1[j]);
            }
        }
    }
}

// ---- conv1 + pool1: block = bucket = 56 nodes. Unordered edge consumption
//      via LDS int32 fixed-point atomics (associative -> deterministic).
//      p1 stored BF16 (64B rows): conv2's random gather traffic halves. ----
__global__ __launch_bounds__(256, 6)
void conv1_pool(const int2* __restrict__ pk0, const int* __restrict__ cnt0,
                const float* __restrict__ x,
                const float* __restrict__ W1,
                const float* __restrict__ root, const float* __restrict__ bias,
                unsigned short* __restrict__ p1b) {
    __shared__ int   Ui[56 * 26];     // 5.8 KB fixed-point taps+deg
    __shared__ float h1t[56 * 32];    // 7.2 KB
    int t = threadIdx.x;
    int bb = blockIdx.x;              // 1400 blocks; nodes bb*56 .. +55
    int n0 = bb * 56;
    for (int i = t; i < 56 * 26; i += 256) Ui[i] = 0;
    __syncthreads();
    int cnt = min(cnt0[bb], CAP0);
    const int2* bkt = pk0 + bb * CAP0;
    for (int j = t; j < cnt; j += 256) {
        int2 r = bkt[j];                              // sequential, coalesced
        int src = r.x & 0xFFFFF, low = (r.x >> 20) & 63;
        float px = (float)((unsigned)r.y & 0xFFFF) * (1.f / 16384.f);
        float py = (float)((unsigned)r.y >> 16) * (1.f / 16384.f);
        int a00, a01, a10, a11; float fx, fy;
        taps4(px, py, a00, a01, a10, a11, fx, fy);
        float xv = x[src];                            // 313KB array: L2-resident
        float gx = 1.f - fx, gy = 1.f - fy;
        int* row = Ui + low * 26;
        atomicAdd(row + a00, __float2int_rn(gx * gy * xv * SC1));
        atomicAdd(row + a01, __float2int_rn(gx * fy * xv * SC1));
        atomicAdd(row + a10, __float2int_rn(fx * gy * xv * SC1));
        atomicAdd(row + a11, __float2int_rn(fx * fy * xv * SC1));
        atomicAdd(row + 25, 1);
    }
    __syncthreads();
    {
        int o = t & 31, ng = t >> 5;
        float w1c[25];
#pragma unroll
        for (int a = 0; a < 25; a++) w1c[a] = W1[a * C1 + o];
        float ro = root[o], bo = bias[o];
        for (int j2 = 0; j2 < 7; j2++) {
            int nl = ng * 7 + j2;
            int n = n0 + nl;
            float acc = 0.f;
#pragma unroll
            for (int a = 0; a < 25; a++) acc += (float)Ui[nl * 26 + a] * w1c[a];
            float invd = ISC1 / fmaxf((float)Ui[nl * 26 + 25], 1.f);
            float v = acc * invd + x[n] * ro + bo;
            h1t[nl * 32 + o] = v > 0.f ? v : expm1f(v);
        }
    }
    __syncthreads();
    for (int i2 = t; i2 < 448; i2 += 256) {
        int o2 = i2 & 31, pc = i2 >> 5;
        float m0 = h1t[(2 * pc) * 32 + o2],      m1 = h1t[(2 * pc + 1) * 32 + o2];
        float m2 = h1t[(28 + 2 * pc) * 32 + o2], m3 = h1t[(28 + 2 * pc + 1) * 32 + o2];
        p1b[(bb * 14 + pc) * C1 + o2] = f2bf(fmaxf(fmaxf(m0, m1), fmaxf(m2, m3)));
    }
}

// ---- conv2 fused (MFMA): block = bucket = 16 nodes, 512 threads.
//      Gather reads BF16 p1 rows (64B). Epilogue pools via order-encoded
//      global atomicMax into pmax (exact max, deterministic). ----
__global__ __launch_bounds__(512, 2)
void conv2_fused(const unsigned short* __restrict__ p1b, const int2* __restrict__ pk1,
                 const int* __restrict__ cnt1,
                 const unsigned short* __restrict__ w2t,
                 const float* __restrict__ b2, unsigned* __restrict__ pmax) {
    __shared__ int   Ui[16 * ULS];          // 53.5 KB fixed-point (bf16 aliases)
    __shared__ int   es[CAP1];
    __shared__ int   et[CAP1];
    __shared__ float efx[CAP1], efy[CAP1];
    __shared__ int   degc[16];
    unsigned short* Ub = (unsigned short*)Ui;
    int t = threadIdx.x;
    int bx = blockIdx.x;                    // 1225 blocks; nodes bx*16..+15
    int nb = bx * 16;
    int i = t & 31;                         // channel
    int g = t >> 5;                         // node slot 0..15
    int* up = Ui + g * ULS;
#pragma unroll
    for (int a = 0; a < 25; a++) up[a * 32 + i] = 0;
    up[800 + i] = __float2int_rn(bf2f(p1b[(nb + g) * C1 + i]) * SC2);   // root
    if (t < 16) degc[t] = 0;
    __syncthreads();
    int cnt = min(cnt1[bx], CAP1);
    for (int j = t; j < cnt; j += 512) {
        int2 r = pk1[bx * CAP1 + j];                  // sequential, coalesced
        es[j] = r.x;                                  // src | node<<20
        float px = (float)((unsigned)r.y & 0xFFFF) * (1.f / 16384.f);
        float py = (float)((unsigned)r.y >> 16) * (1.f / 16384.f);
        int a00, a01, a10, a11; float fx, fy;
        taps4(px, py, a00, a01, a10, a11, fx, fy);
        et[j] = a00 | (a01 << 5) | (a10 << 10) | (a11 << 15);
        efx[j] = fx; efy[j] = fy;
        atomicAdd(&degc[(r.x >> 20) & 15], 1);
    }
    __syncthreads();
    // accumulate: thread (slot g, ch i) walks edges g, g+16, ...
    for (int j = g; j < cnt; j += 16) {
        int rx = es[j];
        float xv = bf2f(p1b[(rx & 0xFFFFF) * C1 + i]);
        int* row = Ui + ((rx >> 20) & 15) * ULS;
        int m = et[j];
        float fx = efx[j], fy = efy[j];
        float gx = 1.f - fx, gy = 1.f - fy;
        atomicAdd(row + (m & 31) * 32 + i,         __float2int_rn(gx * gy * xv * SC2));
        atomicAdd(row + ((m >> 5) & 31) * 32 + i,  __float2int_rn(gx * fy * xv * SC2));
        atomicAdd(row + ((m >> 10) & 31) * 32 + i, __float2int_rn(fx * gy * xv * SC2));
        atomicAdd(row + ((m >> 15) & 31) * 32 + i, __float2int_rn(fx * fy * xv * SC2));
    }
    __syncthreads();
    // phase 1.5: int fixed-point -> bf16 (invd folded into tap part)
    {
        int g2 = t >> 5, i2c = t & 31;
        float invd = 1.f / fmaxf((float)degc[g2], 1.f);
        float stap = ISC2 * invd;
        const int* srcp = Ui + g2 * ULS + i2c * 26;
        float rv[26];
#pragma unroll
        for (int j = 0; j < 26; j++) {
            float v = (float)srcp[j];
            rv[j] = (i2c * 26 + j < 800) ? v * stap : v * ISC2;
        }
        __syncthreads();
        unsigned* dstp = (unsigned*)(Ub + g2 * UBS + i2c * 26);
#pragma unroll
        for (int j = 0; j < 13; j++) {
            unsigned lo = f2bf(rv[2 * j]), hi = f2bf(rv[2 * j + 1]);
            dstp[j] = lo | (hi << 16);
        }
    }
    __syncthreads();
    // phase 2: MFMA, waves 0-3. D[node=quad*4+r][o=wv*16+(lane&15)]
    int wv = t >> 6, lane = t & 63, quad = lane >> 4, lrow = lane & 15;
    if (wv < 4) {
        f32x4 acc = {0.f, 0.f, 0.f, 0.f};
        const unsigned short* bbase = w2t + (wv * 16 + lrow) * KEXT;
        const unsigned short* abase = Ub + lrow * UBS;   // A row = node lrow
#pragma unroll
        for (int kc = 0; kc < 26; kc++) {
            bf16x8 a = *(const bf16x8*)(abase + kc * 32 + quad * 8);
            bf16x8 b = *(const bf16x8*)(bbase + kc * 32 + quad * 8);
            acc = __builtin_amdgcn_mfma_f32_16x16x32_bf16(a, b, acc, 0, 0, 0);
        }
        int o = wv * 16 + lrow;
        float bo = b2[o];
#pragma unroll
        for (int r = 0; r < 4; r++) {
            int node = quad * 4 + r;
            float v = acc[r] + bo;
            v = v > 0.f ? v : expm1f(v);
            int n1 = nb + node;
            int b28 = n1 / 784;
            int rem = n1 - b28 * 784;
            int rr = rem / 28, cc = rem - rr * 28;
            int flat = ((b28 * 14 + (rr >> 1)) * 14 + (cc >> 1)) * 64 + o;
            atomicMax(&pmax[flat], fenc(v));
        }
    }
}

// ---- fc1 MFMA: pooled A decoded from pmax during staging; 7 kz splits. ----
__global__ void gemm_fc1(const unsigned* __restrict__ pmax,
                         const unsigned short* __restrict__ wt1,
                         float* __restrict__ z1p) {
    constexpr int AS = 232;
    __shared__ unsigned short as_[16 * AS];
    int t = threadIdx.x;
    int jt = blockIdx.x, mt = blockIdx.y, kz = blockIdx.z;
    int wv = t >> 6, lane = t & 63, quad = lane >> 4, lrow = lane & 15;
    int m0 = mt * 16;
    int kbase = kz * 448;
    const unsigned short* bbase = wt1 + (jt * 64 + wv * 16 + lrow) * FC1_IN + kbase;
    f32x4 acc = {0.f, 0.f, 0.f, 0.f};
    for (int ch = 0; ch < 2; ch++) {
        __syncthreads();
        for (int slot = t; slot < 448; slot += 256) {
            int r = slot / 28, c = slot - (slot / 28) * 28;
            const unsigned* gp = pmax + (m0 + r) * FC1_IN + kbase + ch * 224 + c * 8;
            uint4 e0 = *(const uint4*)gp;
            uint4 e1 = *(const uint4*)(gp + 4);
            unsigned w0 = (unsigned)fdec_bf(e0.x) | ((unsigned)fdec_bf(e0.y) << 16);
            unsigned w1 = (unsigned)fdec_bf(e0.z) | ((unsigned)fdec_bf(e0.w) << 16);
            unsigned w2 = (unsigned)fdec_bf(e1.x) | ((unsigned)fdec_bf(e1.y) << 16);
            unsigned w3 = (unsigned)fdec_bf(e1.z) | ((unsigned)fdec_bf(e1.w) << 16);
            *(uint4*)(as_ + r * AS + c * 8) = make_uint4(w0, w1, w2, w3);
        }
        __syncthreads();
        const unsigned short* ab = as_ + lrow * AS;
        const unsigned short* bb = bbase + ch * 224;
#pragma unroll
        for (int kk = 0; kk < 7; kk++) {
            bf16x8 a = *(const bf16x8*)(ab + kk * 32 + quad * 8);
            bf16x8 b = *(const bf16x8*)(bb + kk * 32 + quad * 8);
            acc = __builtin_amdgcn_mfma_f32_16x16x32_bf16(a, b, acc, 0, 0, 0);
        }
    }
    int n = jt * 64 + wv * 16 + lrow;
#pragma unroll
    for (int r = 0; r < 4; r++) {
        int m = m0 + quad * 4 + r;
        z1p[kz * (112 * FC1_OUT) + m * FC1_OUT + n] = acc[r];
    }
}

// ---- fc2 + log_softmax fused; sums 7 fc1 partials, applies fc1 bias+ELU ----
__global__ void fc2_lsm(const float* __restrict__ z1p, const float* __restrict__ fc1b,
                        const float* __restrict__ w, const float* __restrict__ fc2b,
                        float* __restrict__ out) {
    int b = blockIdx.x;
    int t = threadIdx.x;
    int wv = t >> 6;
    int lane = t & 63;
    float acc = 0.f;
#pragma unroll
    for (int m = 0; m < 8; m++) {
        int k = lane * 8 + m;
        float xv = fc1b[k];
#pragma unroll
        for (int p = 0; p < KZ; p++)
            xv += z1p[p * (112 * FC1_OUT) + b * FC1_OUT + k];
        xv = xv > 0.f ? xv : expm1f(xv);
        acc += xv * w[k * 10 + wv];
    }
#pragma unroll
    for (int off = 32; off > 0; off >>= 1) acc += __shfl_down(acc, off);
    __shared__ float zs[10];
    if (lane == 0) {
        float z = acc + fc2b[wv];
        zs[wv] = z > 0.f ? z : expm1f(z);
    }
    __syncthreads();
    if (t < 10) {
        float m = -1e30f;
        for (int jj = 0; jj < 10; jj++) m = fmaxf(m, zs[jj]);
        float s = 0.f;
        for (int jj = 0; jj < 10; jj++) s += expf(zs[jj] - m);
        out[b * 10 + t] = zs[t] - m - logf(s);
    }
}

extern "C" void kernel_launch(void* const* d_in, const int* in_sizes, int n_in,
                              void* d_out, int out_size, void* d_ws, size_t ws_size,
                              hipStream_t stream) {
    const float* x     = (const float*)d_in[0];
    const float* ps0   = (const float*)d_in[1];
    const float* ps1   = (const float*)d_in[2];
    const float* W1    = (const float*)d_in[3];
    const float* root1 = (const float*)d_in[4];
    const float* b1    = (const float*)d_in[5];
    const float* W2    = (const float*)d_in[6];
    const float* root2 = (const float*)d_in[7];
    const float* b2v   = (const float*)d_in[8];
    const float* fc1w  = (const float*)d_in[9];
    const float* fc1b  = (const float*)d_in[10];
    const float* fc2w  = (const float*)d_in[11];
    const float* fc2b  = (const float*)d_in[12];
    const int*   ei0   = (const int*)d_in[13];
    const int*   ei1   = (const int*)d_in[14];

    // Workspace layout — ALL extents in 4-byte WORDS (ushort arrays: count/2).
    // pk0 = 1400*576 int2 = 1,612,800 w ; pk1 = 1225*224 int2 = 548,800 w
    // p1b = 19600*32 ushorts = 627,200 us = 313,600 w
    // pmax = 112*3136 uint = 351,232 w ; w2t = 64*832 us = 26,624 w
    // wt1 = 512*3136 us = 802,816 w
    float* ws = (float*)d_ws;
    int*  gcur = (int*)ws;                          //      2,625 (pad -> 2,688; memset)
    int2* pk0  = (int2*)(ws + 2688);                //  1,612,800 w
    int2* pk1  = (int2*)(ws + 1615488);             //    548,800 w
    unsigned short* p1b = (unsigned short*)(ws + 2164288);  // 313,600 w
    unsigned* pmax = (unsigned*)(ws + 2477888);     //    351,232 w
    float* z1p = ws + 2829120;                      //    401,408 (7 partials)
    unsigned short* w2t = (unsigned short*)(ws + 3230528);  //  26,624 w
    unsigned short* wt1 = (unsigned short*)(ws + 3257152);  // 802,816 w
    // high water: 4,059,968 words = 16.2 MB

    hipMemsetAsync(gcur, 0, (size_t)NBT * sizeof(int), stream);

    coarse_bin<<<600, 512, 0, stream>>>(ei0, ei1, ps0, ps1, gcur, pk0, pk1,
                                        fc1w, W2, root2, wt1, w2t, pmax);
    conv1_pool<<<NB0, 256, 0, stream>>>(pk0, gcur, x, W1, root1, b1, p1b);
    conv2_fused<<<NB1, 512, 0, stream>>>(p1b, pk1, gcur + NB0, w2t, b2v, pmax);
    gemm_fc1<<<dim3(8, 7, KZ), 256, 0, stream>>>(pmax, wt1, z1p);
    fc2_lsm<<<BSZ, 640, 0, stream>>>(z1p, fc1b, fc2w, fc2b, (float*)d_out);
}